// Round 1
// baseline (289.321 us; speedup 1.0000x reference)
//
#include <hip/hip_runtime.h>

// Problem shape (fixed by the bench):
//   x: (B=32, I=65536) f32 ; w: (I, M=32) f32 ; mapping: (I, M) int in [0, O=65536)
//   out[b, o] = sum_{i,m: map[i,m]==o} w[i,m] * x[b,i]   -> (B, O) f32
static constexpr int B = 32;
static constexpr int I = 65536;
static constexpr int M = 32;
static constexpr int O = 65536;

// ---------------------------------------------------------------------------
// Transpose x (B, I) -> xT (I, B). One 32x32 tile per block (1024 threads).
__global__ __launch_bounds__(1024) void xpose_x(const float* __restrict__ x,
                                                float* __restrict__ xT) {
    __shared__ float tile[32][33];
    const int i0   = blockIdx.x * 32;
    const int lane = threadIdx.x & 31;
    const int row  = threadIdx.x >> 5;
    // coalesced read along I
    tile[row][lane] = x[row * I + i0 + lane];
    __syncthreads();
    // xT[(i0+row)][lane] = x[lane][i0+row] = tile[lane][row]; coalesced write
    xT[(i0 + row) * 32 + lane] = tile[lane][row];
}

// ---------------------------------------------------------------------------
// Main scatter: one thread per (pair, b); pair = i*32+m.
// Half-wave (32 lanes) = 32 b's of one pair -> atomic addresses contiguous.
__global__ __launch_bounds__(256) void scatter_T(const float* __restrict__ w,
                                                 const int* __restrict__ map,
                                                 const float* __restrict__ xT,
                                                 float* __restrict__ outT) {
    const int tid  = blockIdx.x * 256 + threadIdx.x;
    const int b    = tid & 31;
    const int pair = tid >> 5;          // i*32 + m
    const int i    = pair >> 5;
    const int o    = map[pair] & (O - 1);   // pow2 mask: safety vs dtype surprises
    const float v  = w[pair] * xT[i * 32 + b];
    atomicAdd(&outT[o * 32 + b], v);
}

// Fallback (small ws): one thread per pair, direct atomics into out (B, O).
__global__ __launch_bounds__(256) void scatter_direct(const float* __restrict__ x,
                                                      const float* __restrict__ w,
                                                      const int* __restrict__ map,
                                                      float* __restrict__ out) {
    const int pair = blockIdx.x * 256 + threadIdx.x;
    if (pair >= I * M) return;
    const int i   = pair >> 5;
    const int o   = map[pair] & (O - 1);
    const float wv = w[pair];
#pragma unroll
    for (int b = 0; b < B; ++b) {
        atomicAdd(&out[b * O + o], wv * x[b * I + i]);
    }
}

// ---------------------------------------------------------------------------
// Transpose outT (O, B) -> out (B, O). One 32x32 tile per block.
__global__ __launch_bounds__(1024) void xpose_out(const float* __restrict__ outT,
                                                  float* __restrict__ out) {
    __shared__ float tile[32][33];
    const int o0   = blockIdx.x * 32;
    const int lane = threadIdx.x & 31;
    const int row  = threadIdx.x >> 5;
    tile[row][lane] = outT[(o0 + row) * 32 + lane];   // coalesced read
    __syncthreads();
    out[row * O + o0 + lane] = tile[lane][row];        // coalesced write
}

// ---------------------------------------------------------------------------
extern "C" void kernel_launch(void* const* d_in, const int* in_sizes, int n_in,
                              void* d_out, int out_size, void* d_ws, size_t ws_size,
                              hipStream_t stream) {
    const float* x   = (const float*)d_in[0];
    const float* w   = (const float*)d_in[1];
    const int*   map = (const int*)d_in[2];
    float*       out = (float*)d_out;

    const size_t outT_bytes = (size_t)O * B * sizeof(float);   // 8 MB
    const size_t xT_bytes   = (size_t)I * B * sizeof(float);   // 8 MB

    if (ws_size >= outT_bytes + xT_bytes) {
        float* outT = (float*)d_ws;
        float* xT   = (float*)((char*)d_ws + outT_bytes);

        hipMemsetAsync(outT, 0, outT_bytes, stream);
        xpose_x<<<I / 32, 1024, 0, stream>>>(x, xT);

        const int nthreads = I * M * B;                 // 67,108,864
        scatter_T<<<nthreads / 256, 256, 0, stream>>>(w, map, xT, outT);

        xpose_out<<<O / 32, 1024, 0, stream>>>(outT, out);
    } else {
        hipMemsetAsync(out, 0, (size_t)B * O * sizeof(float), stream);
        scatter_direct<<<(I * M) / 256, 256, 0, stream>>>(x, w, map, out);
    }
}